// Round 1
// 1916.005 us; speedup vs baseline: 1.3094x; 1.3094x over previous
//
#include <hip/hip_runtime.h>
#include <math.h>

// Problem constants
#define BB   4
#define LL   4096
#define DIMC 2048
#define SC   128
#define MM   (BB*LL)        // 16384 rows
#define NC   256            // scan chunks per sequence (was 64)
#define LCH  (LL/NC)        // 16 = chunk length

// ---------------------------------------------------------------------------
// Kernel 0: transpose dt_w (S,2*DIM) -> (2*DIM,S) and pg_w (S,DIM) -> (DIM,S)
// ---------------------------------------------------------------------------
__global__ void transpose_w(const float* __restrict__ dt_w,
                            const float* __restrict__ pg_w,
                            float* __restrict__ dtw_t,
                            float* __restrict__ pgw_t) {
    int i = threadIdx.x + blockIdx.x * 256;
    if (i < 2*DIMC*SC) {                 // 4096*128
        int d = i >> 7, s = i & 127;
        dtw_t[i] = dt_w[(size_t)s * (2*DIMC) + d];
    }
    int j = i - 2*DIMC*SC;
    if (j >= 0 && j < DIMC*SC) {         // 2048*128
        int d = j >> 7, s = j & 127;
        pgw_t[j] = pg_w[(size_t)s * DIMC + d];
    }
}

// ---------------------------------------------------------------------------
// Kernel 1: fused projections. Block = 512 threads: (s:128) x (row-group:4).
// 32 rows/block, 8 rows/thread -> 32 fp32 accumulators/thread.
// Grid stays 512 blocks (= 2 blocks/CU) but waves/CU doubles 8 -> 16
// (occupancy 24% -> ~47%): the L2-latency on per-iteration weight loads
// was exposed at 2 waves/SIMD (VALUBusy 52%).
// ---------------------------------------------------------------------------
__global__ __launch_bounds__(512, 4) void phase1(
    const float* __restrict__ x,        // (M, DIM, 2)
    const float* __restrict__ dtw_t,    // (4096, 128)
    const float* __restrict__ pgw_t,    // (2048, 128)
    const float* __restrict__ Br,       // (2048, 128)
    const float* __restrict__ Bi,       // (2048, 128)
    const float* __restrict__ log_A_real,
    const float* __restrict__ log_A_imag,
    const float* __restrict__ dt_b,
    const float* __restrict__ dt_bias,
    const float* __restrict__ pg_b,
    float* __restrict__ Abuf,
    float* __restrict__ Bxbuf)
{
    const int s     = threadIdx.x & 127;   // 0..127 (wave-contiguous)
    const int g     = threadIdx.x >> 7;    // 0..3 row-group
    const int rbase = g * 8;
    const int m0    = blockIdx.x * 32;

    __shared__ __align__(16) float2 xs[32][64];   // 16 KB  (xr, xi)
    __shared__ __align__(16) float  cs[32][64];   // 8 KB   |x|

    float accd[8], accp[8], accbr[8], accbi[8];
    #pragma unroll
    for (int r = 0; r < 8; ++r) { accd[r]=0.f; accp[r]=0.f; accbr[r]=0.f; accbi[r]=0.f; }

    const float2* x2 = (const float2*)x;

    for (int kt = 0; kt < DIMC; kt += 64) {
        __syncthreads();
        #pragma unroll
        for (int j = 0; j < 4; ++j) {
            int i  = threadIdx.x + j * 512;
            int r  = i >> 6, kk = i & 63;
            float2 xv = x2[(size_t)(m0 + r) * DIMC + kt + kk];
            xs[r][kk] = xv;
            cs[r][kk] = sqrtf(fmaf(xv.x, xv.x, xv.y * xv.y));
        }
        __syncthreads();

        const float* wdr_p = dtw_t + (size_t)kt * SC + s;
        const float* wdi_p = dtw_t + (size_t)(DIMC + kt) * SC + s;
        const float* wbr_p = Br    + (size_t)kt * SC + s;
        const float* wbi_p = Bi    + (size_t)kt * SC + s;
        const float* wpg_p = pgw_t + (size_t)kt * SC + s;

        for (int kk = 0; kk < 64; kk += 2) {
            float w0dr = wdr_p[(size_t)kk*SC],     w1dr = wdr_p[(size_t)(kk+1)*SC];
            float w0di = wdi_p[(size_t)kk*SC],     w1di = wdi_p[(size_t)(kk+1)*SC];
            float w0br = wbr_p[(size_t)kk*SC],     w1br = wbr_p[(size_t)(kk+1)*SC];
            float w0bi = wbi_p[(size_t)kk*SC],     w1bi = wbi_p[(size_t)(kk+1)*SC];
            float w0pg = wpg_p[(size_t)kk*SC],     w1pg = wpg_p[(size_t)(kk+1)*SC];
            #pragma unroll
            for (int r2 = 0; r2 < 8; ++r2) {
                const int r = rbase + r2;
                float4 xv = *(const float4*)&xs[r][kk];   // (xr0,xi0,xr1,xi1)
                float2 cb = *(const float2*)&cs[r][kk];
                accd[r2]  = fmaf(xv.x,  w0dr, accd[r2]);
                accd[r2]  = fmaf(xv.y,  w0di, accd[r2]);
                accbr[r2] = fmaf(xv.x,  w0br, accbr[r2]);
                accbr[r2] = fmaf(-xv.y, w0bi, accbr[r2]);
                accbi[r2] = fmaf(xv.x,  w0bi, accbi[r2]);
                accbi[r2] = fmaf(xv.y,  w0br, accbi[r2]);
                accp[r2]  = fmaf(cb.x,  w0pg, accp[r2]);
                accd[r2]  = fmaf(xv.z,  w1dr, accd[r2]);
                accd[r2]  = fmaf(xv.w,  w1di, accd[r2]);
                accbr[r2] = fmaf(xv.z,  w1br, accbr[r2]);
                accbr[r2] = fmaf(-xv.w, w1bi, accbr[r2]);
                accbi[r2] = fmaf(xv.z,  w1bi, accbi[r2]);
                accbi[r2] = fmaf(xv.w,  w1br, accbi[r2]);
                accp[r2]  = fmaf(cb.y,  w1pg, accp[r2]);
            }
        }
    }

    // epilogue: dt=softplus, A = p + (1-p)*exp(-dt*eA)*eig, Bx = (1-p)*dt*Bx0
    float eAr   = expf(log_A_real[s]);
    float eig_r = cosf(log_A_imag[s]);
    float eig_i = sinf(log_A_imag[s]);
    float bsum  = dt_b[s] + dt_bias[s];
    float pgb   = pg_b[s];
    float2* A2  = (float2*)Abuf;
    float2* Bx2 = (float2*)Bxbuf;
    #pragma unroll 4
    for (int r2 = 0; r2 < 8; ++r2) {
        float z    = accd[r2] + bsum;
        float dt   = fmaxf(z, 0.f) + log1pf(expf(-fabsf(z)));   // softplus
        float amag = expf(-dt * eAr);
        float zp   = accp[r2] + pgb;
        float pr   = 1.f / (1.f + expf(-zp));
        float omp  = 1.f - pr;
        float Ar_  = fmaf(omp, amag * eig_r, pr);
        float Ai_  = omp * amag * eig_i;
        float sc   = omp * dt;
        size_t base = (size_t)(m0 + rbase + r2) * SC + s;
        A2[base]  = make_float2(Ar_, Ai_);
        Bx2[base] = make_float2(sc * accbr[r2], sc * accbi[r2]);
    }
}

// ---------------------------------------------------------------------------
// Kernel 2a: per-chunk reduce of (A,B) pairs. Grid = B*NC = 1024, block = 128.
// NC=256 (was 64): 4x the waves, 1/4 the serial chain per thread.
// ---------------------------------------------------------------------------
__global__ void scan_reduce(const float* __restrict__ Abuf,
                            const float* __restrict__ Bxbuf,
                            float* __restrict__ aggA,
                            float* __restrict__ aggB) {
    int s = threadIdx.x;
    int c = blockIdx.x & (NC-1);
    int b = blockIdx.x >> 8;
    const float2* A2  = (const float2*)Abuf;
    const float2* Bx2 = (const float2*)Bxbuf;
    size_t base = ((size_t)(b * LL + c * LCH) * SC + s);
    float2 a0 = A2[base], b0 = Bx2[base];
    float ar = a0.x, ai = a0.y, br = b0.x, bi = b0.y;
    #pragma unroll
    for (int l = 1; l < LCH; ++l) {
        float2 al = A2[base + (size_t)l * SC];
        float2 bl = Bx2[base + (size_t)l * SC];
        float nar = ar*al.x - ai*al.y;
        float nai = ar*al.y + ai*al.x;
        float nbr = br*al.x - bi*al.y + bl.x;
        float nbi = br*al.y + bi*al.x + bl.y;
        ar = nar; ai = nai; br = nbr; bi = nbi;
    }
    ((float2*)aggA)[(size_t)blockIdx.x * SC + s] = make_float2(ar, ai);
    ((float2*)aggB)[(size_t)blockIdx.x * SC + s] = make_float2(br, bi);
}

// ---------------------------------------------------------------------------
// Kernel 2b: exclusive scan of chunk aggregates (spine). 512 threads total.
// ---------------------------------------------------------------------------
__global__ void scan_spine(const float* __restrict__ aggA,
                           const float* __restrict__ aggB,
                           float* __restrict__ preB) {
    int t = threadIdx.x + blockIdx.x * blockDim.x;   // 0..511
    int s = t & 127, b = t >> 7;
    const float2* A2 = (const float2*)aggA;
    const float2* B2 = (const float2*)aggB;
    float2* P2 = (float2*)preB;
    float pa_r = 1.f, pa_i = 0.f, pb_r = 0.f, pb_i = 0.f;
    for (int c = 0; c < NC; ++c) {
        size_t idx = (size_t)(b * NC + c) * SC + s;
        P2[idx] = make_float2(pb_r, pb_i);
        float2 a = A2[idx], bb = B2[idx];
        float nar = pa_r*a.x - pa_i*a.y;
        float nai = pa_r*a.y + pa_i*a.x;
        float nbr = pb_r*a.x - pb_i*a.y + bb.x;
        float nbi = pb_r*a.y + pb_i*a.x + bb.y;
        pa_r = nar; pa_i = nai; pb_r = nbr; pb_i = nbi;
    }
}

// ---------------------------------------------------------------------------
// Kernel 2c: apply prefixes, write h (and h_last output). Grid = B*NC = 1024.
// ---------------------------------------------------------------------------
__global__ void scan_apply(const float* __restrict__ Abuf,
                           const float* __restrict__ Bxbuf,
                           const float* __restrict__ preB,
                           float* __restrict__ hbuf,
                           float* __restrict__ d_out) {
    int s = threadIdx.x;
    int c = blockIdx.x & (NC-1);
    int b = blockIdx.x >> 8;
    const float2* A2  = (const float2*)Abuf;
    const float2* Bx2 = (const float2*)Bxbuf;
    float2 hp = ((const float2*)preB)[(size_t)blockIdx.x * SC + s];
    float hr = hp.x, hi = hp.y;
    size_t base = ((size_t)(b * LL + c * LCH) * SC + s);
    float2* h2 = (float2*)hbuf;
    #pragma unroll
    for (int l = 0; l < LCH; ++l) {
        float2 al = A2[base + (size_t)l * SC];
        float2 bl = Bx2[base + (size_t)l * SC];
        float nr = al.x*hr - al.y*hi + bl.x;
        float ni = al.x*hi + al.y*hr + bl.y;
        hr = nr; hi = ni;
        h2[base + (size_t)l * SC] = make_float2(hr, hi);
    }
    if (c == NC - 1) {   // l = L-1 -> h_last
        float2* hl = (float2*)(d_out + (size_t)MM * DIMC * 2);
        hl[b * SC + s] = make_float2(hr, hi);
    }
}

// ---------------------------------------------------------------------------
// Kernel 3: y = h @ (Cr + i Ci) + D*x. Block = 256 (d), 16 rows/block.
// Grid = 1024 blocks -> 4 blocks/CU (was 2), occupancy 25% -> ~50%.
// s processed in pairs -> ds_read_b128 (8 FMAs per LDS instr).
// ---------------------------------------------------------------------------
__global__ __launch_bounds__(256, 4) void phase3(
    const float* __restrict__ hbuf,
    const float* __restrict__ Cr,      // (S, DIM)
    const float* __restrict__ Ci,      // (S, DIM)
    const float* __restrict__ x,       // (M, DIM, 2)
    const float* __restrict__ Dw,      // (DIM, 2)
    float* __restrict__ out)
{
    const int tid = threadIdx.x;
    const int m0  = blockIdx.x * 16;
    __shared__ __align__(16) float2 hs[16][128];   // 16 KB
    const float2* h2 = (const float2*)hbuf;
    #pragma unroll
    for (int j = 0; j < 8; ++j) {
        int i = tid + j * 256;
        hs[i >> 7][i & 127] = h2[(size_t)(m0 + (i >> 7)) * SC + (i & 127)];
    }
    __syncthreads();

    const float2* x2 = (const float2*)x;
    float2* o2 = (float2*)out;

    for (int d0 = 0; d0 < DIMC; d0 += 256) {
        int d = d0 + tid;
        float yr[16], yi[16];
        #pragma unroll
        for (int r = 0; r < 16; ++r) { yr[r] = 0.f; yi[r] = 0.f; }
        for (int s = 0; s < SC; s += 2) {
            float cr0 = Cr[(size_t)s * DIMC + d];
            float ci0 = Ci[(size_t)s * DIMC + d];
            float cr1 = Cr[(size_t)(s+1) * DIMC + d];
            float ci1 = Ci[(size_t)(s+1) * DIMC + d];
            #pragma unroll
            for (int r = 0; r < 16; ++r) {
                float4 h = *(const float4*)&hs[r][s];   // (hr0,hi0,hr1,hi1)
                yr[r] = fmaf(h.x,  cr0, yr[r]);
                yr[r] = fmaf(-h.y, ci0, yr[r]);
                yi[r] = fmaf(h.x,  ci0, yi[r]);
                yi[r] = fmaf(h.y,  cr0, yi[r]);
                yr[r] = fmaf(h.z,  cr1, yr[r]);
                yr[r] = fmaf(-h.w, ci1, yr[r]);
                yi[r] = fmaf(h.z,  ci1, yi[r]);
                yi[r] = fmaf(h.w,  cr1, yi[r]);
            }
        }
        float dre = Dw[d*2], dim_ = Dw[d*2 + 1];
        #pragma unroll 4
        for (int r = 0; r < 16; ++r) {
            size_t m = (size_t)(m0 + r);
            float2 xv = x2[m * DIMC + d];
            float orr = yr[r] + dre * xv.x - dim_ * xv.y;
            float oii = yi[r] + dre * xv.y + dim_ * xv.x;
            o2[m * DIMC + d] = make_float2(orr, oii);
        }
    }
}

// ---------------------------------------------------------------------------
extern "C" void kernel_launch(void* const* d_in, const int* in_sizes, int n_in,
                              void* d_out, int out_size, void* d_ws, size_t ws_size,
                              hipStream_t stream) {
    const float* x          = (const float*)d_in[0];
    const float* log_A_real = (const float*)d_in[1];
    const float* log_A_imag = (const float*)d_in[2];
    const float* Dw         = (const float*)d_in[3];
    const float* dt_w       = (const float*)d_in[4];
    const float* dt_b       = (const float*)d_in[5];
    const float* dt_bias    = (const float*)d_in[6];
    const float* Br         = (const float*)d_in[7];
    const float* Bi         = (const float*)d_in[8];
    const float* Cr         = (const float*)d_in[9];
    const float* Ci         = (const float*)d_in[10];
    const float* pg_w       = (const float*)d_in[11];
    const float* pg_b       = (const float*)d_in[12];

    float* out = (float*)d_out;
    float* ws  = (float*)d_ws;

    float* dtw_t = ws;                        // 524288 floats
    float* pgw_t = dtw_t + 2*DIMC*SC;         // 262144
    float* Abuf  = pgw_t + DIMC*SC;           // 4194304 (M*S complex)
    float* Bxbuf = Abuf  + (size_t)MM*SC*2;   // 4194304
    float* hbuf  = Bxbuf + (size_t)MM*SC*2;   // 4194304
    // scan aggregates (3 x B*NC*S*2 = 786432 floats) reuse the
    // transposed-weight space, which is dead after phase1 completes.
    float* aggA  = ws;                        // 262144
    float* aggB  = ws + (size_t)BB*NC*SC*2;   // 262144
    float* preB  = ws + (size_t)2*BB*NC*SC*2; // 262144 (ends exactly at Abuf)

    hipLaunchKernelGGL(transpose_w, dim3(3072), dim3(256), 0, stream,
                       dt_w, pg_w, dtw_t, pgw_t);
    hipLaunchKernelGGL(phase1, dim3(MM/32), dim3(512), 0, stream,
                       x, dtw_t, pgw_t, Br, Bi, log_A_real, log_A_imag,
                       dt_b, dt_bias, pg_b, Abuf, Bxbuf);
    hipLaunchKernelGGL(scan_reduce, dim3(BB*NC), dim3(128), 0, stream,
                       Abuf, Bxbuf, aggA, aggB);
    hipLaunchKernelGGL(scan_spine, dim3(2), dim3(256), 0, stream,
                       aggA, aggB, preB);
    hipLaunchKernelGGL(scan_apply, dim3(BB*NC), dim3(128), 0, stream,
                       Abuf, Bxbuf, preB, hbuf, out);
    hipLaunchKernelGGL(phase3, dim3(MM/16), dim3(256), 0, stream,
                       hbuf, Cr, Ci, x, Dw, out);
}

// Round 2
// 1820.004 us; speedup vs baseline: 1.3784x; 1.0527x over previous
//
#include <hip/hip_runtime.h>
#include <math.h>

// Problem constants
#define BB   4
#define LL   4096
#define DIMC 2048
#define SC   128
#define MM   (BB*LL)        // 16384 rows
#define NC   256            // scan chunks per sequence
#define LCH  (LL/NC)        // 16 = chunk length

// ---------------------------------------------------------------------------
// Kernel 0: transpose dt_w (S,2*DIM) -> (2*DIM,S) and pg_w (S,DIM) -> (DIM,S)
// ---------------------------------------------------------------------------
__global__ void transpose_w(const float* __restrict__ dt_w,
                            const float* __restrict__ pg_w,
                            float* __restrict__ dtw_t,
                            float* __restrict__ pgw_t) {
    int i = threadIdx.x + blockIdx.x * 256;
    if (i < 2*DIMC*SC) {                 // 4096*128
        int d = i >> 7, s = i & 127;
        dtw_t[i] = dt_w[(size_t)s * (2*DIMC) + d];
    }
    int j = i - 2*DIMC*SC;
    if (j >= 0 && j < DIMC*SC) {         // 2048*128
        int d = j >> 7, s = j & 127;
        pgw_t[j] = pg_w[(size_t)s * DIMC + d];
    }
}

// ---------------------------------------------------------------------------
// Kernel 1: fused projections.
// Block = 256 threads = (s-pair lane: 64) x (row-group: 4). 32 rows/block.
// Per-thread tile: 8 rows x 2 s -> 64 float2 accumulators.
// vs round-1 (8x1 tile): per kk-pair 224 FMA against the SAME 16 ds_reads
// and 10 weight-load instrs (now float2) -> FMA fraction of VALU ~2x.
// Occupancy is grid-capped at 2 blocks/CU (8 waves) -- latency hidden by
// 64 independent acc chains (ILP), not TLP. K-tile = 128 halves barriers.
// ---------------------------------------------------------------------------
__global__ __launch_bounds__(256, 2) void phase1(
    const float* __restrict__ x,        // (M, DIM, 2)
    const float* __restrict__ dtw_t,    // (4096, 128)
    const float* __restrict__ pgw_t,    // (2048, 128)
    const float* __restrict__ Br,       // (2048, 128)
    const float* __restrict__ Bi,       // (2048, 128)
    const float* __restrict__ log_A_real,
    const float* __restrict__ log_A_imag,
    const float* __restrict__ dt_b,
    const float* __restrict__ dt_bias,
    const float* __restrict__ pg_b,
    float* __restrict__ ABx)            // (M, S) float4: (Ar,Ai,Bxr,Bxi)
{
    const int l     = threadIdx.x & 63;   // s-pair lane: covers s=2l, 2l+1
    const int g     = threadIdx.x >> 6;   // 0..3 row-group
    const int rbase = g * 8;
    const int m0    = blockIdx.x * 32;

    __shared__ __align__(16) float2 xs[32][128];   // 32 KB  (xr, xi)
    __shared__ __align__(16) float  cs[32][128];   // 16 KB  |x|

    float2 accd[8], accp[8], accbr[8], accbi[8];
    #pragma unroll
    for (int r = 0; r < 8; ++r) {
        accd[r]  = make_float2(0.f, 0.f);
        accp[r]  = make_float2(0.f, 0.f);
        accbr[r] = make_float2(0.f, 0.f);
        accbi[r] = make_float2(0.f, 0.f);
    }

    const float2* x2 = (const float2*)x;

    for (int kt = 0; kt < DIMC; kt += 128) {
        __syncthreads();
        // stage 32 rows x 128 d: 2048 float4 / 256 threads = 8 iters
        #pragma unroll
        for (int j = 0; j < 8; ++j) {
            int i  = threadIdx.x + j * 256;
            int r  = i >> 6, kp = (i & 63) * 2;
            float4 xv = *(const float4*)&x2[(size_t)(m0 + r) * DIMC + kt + kp];
            *(float4*)&xs[r][kp] = xv;
            cs[r][kp]     = sqrtf(fmaf(xv.x, xv.x, xv.y * xv.y));
            cs[r][kp + 1] = sqrtf(fmaf(xv.z, xv.z, xv.w * xv.w));
        }
        __syncthreads();

        const float2* wdr_p = (const float2*)(dtw_t + (size_t)kt * SC) + l;
        const float2* wdi_p = (const float2*)(dtw_t + (size_t)(DIMC + kt) * SC) + l;
        const float2* wbr_p = (const float2*)(Br    + (size_t)kt * SC) + l;
        const float2* wbi_p = (const float2*)(Bi    + (size_t)kt * SC) + l;
        const float2* wpg_p = (const float2*)(pgw_t + (size_t)kt * SC) + l;

        for (int kk = 0; kk < 128; kk += 2) {
            float2 w0dr = wdr_p[(size_t)kk*64], w1dr = wdr_p[(size_t)(kk+1)*64];
            float2 w0di = wdi_p[(size_t)kk*64], w1di = wdi_p[(size_t)(kk+1)*64];
            float2 w0br = wbr_p[(size_t)kk*64], w1br = wbr_p[(size_t)(kk+1)*64];
            float2 w0bi = wbi_p[(size_t)kk*64], w1bi = wbi_p[(size_t)(kk+1)*64];
            float2 w0pg = wpg_p[(size_t)kk*64], w1pg = wpg_p[(size_t)(kk+1)*64];
            #pragma unroll
            for (int r2 = 0; r2 < 8; ++r2) {
                const int r = rbase + r2;
                float4 xv = *(const float4*)&xs[r][kk];   // (xr0,xi0,xr1,xi1)
                float2 cb = *(const float2*)&cs[r][kk];
                // s0 component
                accd[r2].x  = fmaf(xv.x,  w0dr.x, accd[r2].x);
                accd[r2].x  = fmaf(xv.y,  w0di.x, accd[r2].x);
                accd[r2].x  = fmaf(xv.z,  w1dr.x, accd[r2].x);
                accd[r2].x  = fmaf(xv.w,  w1di.x, accd[r2].x);
                accbr[r2].x = fmaf(xv.x,  w0br.x, accbr[r2].x);
                accbr[r2].x = fmaf(-xv.y, w0bi.x, accbr[r2].x);
                accbr[r2].x = fmaf(xv.z,  w1br.x, accbr[r2].x);
                accbr[r2].x = fmaf(-xv.w, w1bi.x, accbr[r2].x);
                accbi[r2].x = fmaf(xv.x,  w0bi.x, accbi[r2].x);
                accbi[r2].x = fmaf(xv.y,  w0br.x, accbi[r2].x);
                accbi[r2].x = fmaf(xv.z,  w1bi.x, accbi[r2].x);
                accbi[r2].x = fmaf(xv.w,  w1br.x, accbi[r2].x);
                accp[r2].x  = fmaf(cb.x,  w0pg.x, accp[r2].x);
                accp[r2].x  = fmaf(cb.y,  w1pg.x, accp[r2].x);
                // s1 component
                accd[r2].y  = fmaf(xv.x,  w0dr.y, accd[r2].y);
                accd[r2].y  = fmaf(xv.y,  w0di.y, accd[r2].y);
                accd[r2].y  = fmaf(xv.z,  w1dr.y, accd[r2].y);
                accd[r2].y  = fmaf(xv.w,  w1di.y, accd[r2].y);
                accbr[r2].y = fmaf(xv.x,  w0br.y, accbr[r2].y);
                accbr[r2].y = fmaf(-xv.y, w0bi.y, accbr[r2].y);
                accbr[r2].y = fmaf(xv.z,  w1br.y, accbr[r2].y);
                accbr[r2].y = fmaf(-xv.w, w1bi.y, accbr[r2].y);
                accbi[r2].y = fmaf(xv.x,  w0bi.y, accbi[r2].y);
                accbi[r2].y = fmaf(xv.y,  w0br.y, accbi[r2].y);
                accbi[r2].y = fmaf(xv.z,  w1bi.y, accbi[r2].y);
                accbi[r2].y = fmaf(xv.w,  w1br.y, accbi[r2].y);
                accp[r2].y  = fmaf(cb.x,  w0pg.y, accp[r2].y);
                accp[r2].y  = fmaf(cb.y,  w1pg.y, accp[r2].y);
            }
        }
    }

    // epilogue: dt=softplus, A = p + (1-p)*exp(-dt*eA)*eig, Bx = (1-p)*dt*Bx0
    const float2* lar2 = (const float2*)log_A_real;
    const float2* lai2 = (const float2*)log_A_imag;
    const float2* dtb2 = (const float2*)dt_b;
    const float2* dtB2 = (const float2*)dt_bias;
    const float2* pgb2 = (const float2*)pg_b;
    float2 la  = lar2[l];
    float2 eAr = make_float2(expf(la.x), expf(la.y));
    float2 li  = lai2[l];
    float2 egr = make_float2(cosf(li.x), cosf(li.y));
    float2 egi = make_float2(sinf(li.x), sinf(li.y));
    float2 tb  = dtb2[l], tB = dtB2[l];
    float2 bsum = make_float2(tb.x + tB.x, tb.y + tB.y);
    float2 pgb  = pgb2[l];
    float4* AB4 = (float4*)ABx;
    #pragma unroll
    for (int r2 = 0; r2 < 8; ++r2) {
        size_t m = (size_t)(m0 + rbase + r2);
        {   // s = 2l
            float z    = accd[r2].x + bsum.x;
            float dt   = fmaxf(z, 0.f) + log1pf(expf(-fabsf(z)));
            float amag = expf(-dt * eAr.x);
            float zp   = accp[r2].x + pgb.x;
            float pr   = 1.f / (1.f + expf(-zp));
            float omp  = 1.f - pr;
            float Ar_  = fmaf(omp, amag * egr.x, pr);
            float Ai_  = omp * amag * egi.x;
            float sc   = omp * dt;
            AB4[m * SC + 2*l]   = make_float4(Ar_, Ai_, sc * accbr[r2].x, sc * accbi[r2].x);
        }
        {   // s = 2l+1
            float z    = accd[r2].y + bsum.y;
            float dt   = fmaxf(z, 0.f) + log1pf(expf(-fabsf(z)));
            float amag = expf(-dt * eAr.y);
            float zp   = accp[r2].y + pgb.y;
            float pr   = 1.f / (1.f + expf(-zp));
            float omp  = 1.f - pr;
            float Ar_  = fmaf(omp, amag * egr.y, pr);
            float Ai_  = omp * amag * egi.y;
            float sc   = omp * dt;
            AB4[m * SC + 2*l+1] = make_float4(Ar_, Ai_, sc * accbr[r2].y, sc * accbi[r2].y);
        }
    }
}

// ---------------------------------------------------------------------------
// Kernel 2a: per-chunk reduce of (A,B) pairs. Grid = B*NC = 1024, block = 128.
// ABx interleaved float4 -> one load per step (was two float2).
// ---------------------------------------------------------------------------
__global__ void scan_reduce(const float* __restrict__ ABx,
                            float* __restrict__ aggAB) {
    int s = threadIdx.x;
    int c = blockIdx.x & (NC-1);
    int b = blockIdx.x >> 8;
    const float4* AB4 = (const float4*)ABx;
    size_t base = ((size_t)(b * LL + c * LCH) * SC + s);
    float4 v = AB4[base];
    float ar = v.x, ai = v.y, br = v.z, bi = v.w;
    #pragma unroll
    for (int t = 1; t < LCH; ++t) {
        float4 u = AB4[base + (size_t)t * SC];
        float nar = ar*u.x - ai*u.y;
        float nai = ar*u.y + ai*u.x;
        float nbr = br*u.x - bi*u.y + u.z;
        float nbi = br*u.y + bi*u.x + u.w;
        ar = nar; ai = nai; br = nbr; bi = nbi;
    }
    ((float4*)aggAB)[(size_t)blockIdx.x * SC + s] = make_float4(ar, ai, br, bi);
}

// ---------------------------------------------------------------------------
// Kernel 2b: exclusive scan of chunk aggregates (spine). 512 threads total.
// ---------------------------------------------------------------------------
__global__ void scan_spine(const float* __restrict__ aggAB,
                           float* __restrict__ preB) {
    int t = threadIdx.x + blockIdx.x * blockDim.x;   // 0..511
    int s = t & 127, b = t >> 7;
    const float4* A4 = (const float4*)aggAB;
    float2* P2 = (float2*)preB;
    float pa_r = 1.f, pa_i = 0.f, pb_r = 0.f, pb_i = 0.f;
    for (int c = 0; c < NC; ++c) {
        size_t idx = (size_t)(b * NC + c) * SC + s;
        P2[idx] = make_float2(pb_r, pb_i);
        float4 a = A4[idx];
        float nar = pa_r*a.x - pa_i*a.y;
        float nai = pa_r*a.y + pa_i*a.x;
        float nbr = pb_r*a.x - pb_i*a.y + a.z;
        float nbi = pb_r*a.y + pb_i*a.x + a.w;
        pa_r = nar; pa_i = nai; pb_r = nbr; pb_i = nbi;
    }
}

// ---------------------------------------------------------------------------
// Kernel 2c: apply prefixes, write h (and h_last output). Grid = B*NC = 1024.
// ---------------------------------------------------------------------------
__global__ void scan_apply(const float* __restrict__ ABx,
                           const float* __restrict__ preB,
                           float* __restrict__ hbuf,
                           float* __restrict__ d_out) {
    int s = threadIdx.x;
    int c = blockIdx.x & (NC-1);
    int b = blockIdx.x >> 8;
    const float4* AB4 = (const float4*)ABx;
    float2 hp = ((const float2*)preB)[(size_t)blockIdx.x * SC + s];
    float hr = hp.x, hi = hp.y;
    size_t base = ((size_t)(b * LL + c * LCH) * SC + s);
    float2* h2 = (float2*)hbuf;
    #pragma unroll
    for (int t = 0; t < LCH; ++t) {
        float4 u = AB4[base + (size_t)t * SC];
        float nr = u.x*hr - u.y*hi + u.z;
        float ni = u.x*hi + u.y*hr + u.w;
        hr = nr; hi = ni;
        h2[base + (size_t)t * SC] = make_float2(hr, hi);
    }
    if (c == NC - 1) {   // t = L-1 -> h_last
        float2* hl = (float2*)(d_out + (size_t)MM * DIMC * 2);
        hl[b * SC + s] = make_float2(hr, hi);
    }
}

// ---------------------------------------------------------------------------
// Kernel 3: y = h @ (Cr + i Ci) + D*x. Block = 256 (d), 16 rows/block.
// Grid = 1024 blocks -> 4 blocks/CU, 16 waves/CU.
// ---------------------------------------------------------------------------
__global__ __launch_bounds__(256, 4) void phase3(
    const float* __restrict__ hbuf,
    const float* __restrict__ Cr,      // (S, DIM)
    const float* __restrict__ Ci,      // (S, DIM)
    const float* __restrict__ x,       // (M, DIM, 2)
    const float* __restrict__ Dw,      // (DIM, 2)
    float* __restrict__ out)
{
    const int tid = threadIdx.x;
    const int m0  = blockIdx.x * 16;
    __shared__ __align__(16) float2 hs[16][128];   // 16 KB
    const float2* h2 = (const float2*)hbuf;
    #pragma unroll
    for (int j = 0; j < 8; ++j) {
        int i = tid + j * 256;
        hs[i >> 7][i & 127] = h2[(size_t)(m0 + (i >> 7)) * SC + (i & 127)];
    }
    __syncthreads();

    const float2* x2 = (const float2*)x;
    float2* o2 = (float2*)out;

    for (int d0 = 0; d0 < DIMC; d0 += 256) {
        int d = d0 + tid;
        float yr[16], yi[16];
        #pragma unroll
        for (int r = 0; r < 16; ++r) { yr[r] = 0.f; yi[r] = 0.f; }
        for (int s = 0; s < SC; s += 2) {
            float cr0 = Cr[(size_t)s * DIMC + d];
            float ci0 = Ci[(size_t)s * DIMC + d];
            float cr1 = Cr[(size_t)(s+1) * DIMC + d];
            float ci1 = Ci[(size_t)(s+1) * DIMC + d];
            #pragma unroll
            for (int r = 0; r < 16; ++r) {
                float4 h = *(const float4*)&hs[r][s];   // (hr0,hi0,hr1,hi1)
                yr[r] = fmaf(h.x,  cr0, yr[r]);
                yr[r] = fmaf(-h.y, ci0, yr[r]);
                yi[r] = fmaf(h.x,  ci0, yi[r]);
                yi[r] = fmaf(h.y,  cr0, yi[r]);
                yr[r] = fmaf(h.z,  cr1, yr[r]);
                yr[r] = fmaf(-h.w, ci1, yr[r]);
                yi[r] = fmaf(h.z,  ci1, yi[r]);
                yi[r] = fmaf(h.w,  cr1, yi[r]);
            }
        }
        float dre = Dw[d*2], dim_ = Dw[d*2 + 1];
        #pragma unroll 4
        for (int r = 0; r < 16; ++r) {
            size_t m = (size_t)(m0 + r);
            float2 xv = x2[m * DIMC + d];
            float orr = yr[r] + dre * xv.x - dim_ * xv.y;
            float oii = yi[r] + dre * xv.y + dim_ * xv.x;
            o2[m * DIMC + d] = make_float2(orr, oii);
        }
    }
}

// ---------------------------------------------------------------------------
extern "C" void kernel_launch(void* const* d_in, const int* in_sizes, int n_in,
                              void* d_out, int out_size, void* d_ws, size_t ws_size,
                              hipStream_t stream) {
    const float* x          = (const float*)d_in[0];
    const float* log_A_real = (const float*)d_in[1];
    const float* log_A_imag = (const float*)d_in[2];
    const float* Dw         = (const float*)d_in[3];
    const float* dt_w       = (const float*)d_in[4];
    const float* dt_b       = (const float*)d_in[5];
    const float* dt_bias    = (const float*)d_in[6];
    const float* Br         = (const float*)d_in[7];
    const float* Bi         = (const float*)d_in[8];
    const float* Cr         = (const float*)d_in[9];
    const float* Ci         = (const float*)d_in[10];
    const float* pg_w       = (const float*)d_in[11];
    const float* pg_b       = (const float*)d_in[12];

    float* out = (float*)d_out;
    float* ws  = (float*)d_ws;

    float* dtw_t = ws;                        // 524288 floats
    float* pgw_t = dtw_t + 2*DIMC*SC;         // 262144
    float* ABx   = pgw_t + DIMC*SC;           // 8388608 (M*S float4)
    float* hbuf  = ABx + (size_t)MM*SC*4;     // 4194304 (M*S complex)
    // scan aggregates reuse the transposed-weight region (dead after phase1):
    float* aggAB = ws;                        // B*NC*S*4 = 524288
    float* preB  = ws + (size_t)BB*NC*SC*4;   // B*NC*S*2 = 262144 (ends at ABx)

    hipLaunchKernelGGL(transpose_w, dim3(3072), dim3(256), 0, stream,
                       dt_w, pg_w, dtw_t, pgw_t);
    hipLaunchKernelGGL(phase1, dim3(MM/32), dim3(256), 0, stream,
                       x, dtw_t, pgw_t, Br, Bi, log_A_real, log_A_imag,
                       dt_b, dt_bias, pg_b, ABx);
    hipLaunchKernelGGL(scan_reduce, dim3(BB*NC), dim3(128), 0, stream,
                       ABx, aggAB);
    hipLaunchKernelGGL(scan_spine, dim3(2), dim3(256), 0, stream,
                       aggAB, preB);
    hipLaunchKernelGGL(scan_apply, dim3(BB*NC), dim3(128), 0, stream,
                       ABx, preB, hbuf, out);
    hipLaunchKernelGGL(phase3, dim3(MM/16), dim3(256), 0, stream,
                       hbuf, Cr, Ci, x, Dw, out);
}

// Round 4
// 1062.424 us; speedup vs baseline: 2.3613x; 1.7131x over previous
//
#include <hip/hip_runtime.h>
#include <math.h>

// Problem constants
#define BB   4
#define LL   4096
#define DIMC 2048
#define SC   128
#define MM   (BB*LL)        // 16384 rows
#define NC   256            // scan chunks per sequence
#define LCH  (LL/NC)        // 16 = chunk length

typedef __attribute__((ext_vector_type(8))) short bf16x8;
typedef __attribute__((ext_vector_type(4))) float f32x4;

#define MFMA(a,b,c) __builtin_amdgcn_mfma_f32_16x16x32_bf16(a,b,c,0,0,0)

// RNE float -> bf16 bits
__device__ inline unsigned short bf16h(float v) {
    unsigned u = __float_as_uint(v);
    return (unsigned short)((u + 0x7FFFu + ((u >> 16) & 1u)) >> 16);
}
__device__ inline float bf2f(unsigned short h) {
    return __uint_as_float(((unsigned)h) << 16);
}

// ---------------------------------------------------------------------------
// Kernel 0: build fragment-linear bf16 hi/lo weights.
// MFMA 16x16x32 fragment: slot = (ktile*NF + nfrag)*64 + lane, 8 bf16/slot:
// element j = W[k = ktile*32 + 8*(lane>>4) + j][n = nfrag*16 + (lane&15)].
// W1 (K=4096, N=384): n 0..127 dt ([xr;xi] @ dt_w rows), 128..255 Bx_re
// ([Br;-Bi]), 256..383 Bx_im ([Bi;Br]).  W2 (K=2048, N=128): pg_w^T.
// W3 (K=256, N=4096): n = d*2+comp; comp0 (yr): [Cr;-Ci], comp1 (yi): [Ci;Cr].
// ---------------------------------------------------------------------------
#define W1_SLOTS (128*24)
#define W2_SLOTS (64*8)
#define W3_SLOTS (8*256)
__global__ void prep_w(const float* __restrict__ dt_w,
                       const float* __restrict__ Br,
                       const float* __restrict__ Bi,
                       const float* __restrict__ pg_w,
                       const float* __restrict__ Cr,
                       const float* __restrict__ Ci,
                       short* __restrict__ W1h, short* __restrict__ W1l,
                       short* __restrict__ W2h, short* __restrict__ W2l,
                       short* __restrict__ W3h, short* __restrict__ W3l) {
    int id = threadIdx.x + blockIdx.x * 256;
    int lane = id & 63;
    int slot = id >> 6;
    float v[8];
    short* dsth; short* dstl;
    if (slot < W1_SLOTS) {
        int kt = slot / 24, nf = slot % 24;
        int n  = nf * 16 + (lane & 15);
        int k0 = kt * 32 + 8 * (lane >> 4);
        if (n < 128) {
            const float* p = dt_w + (size_t)n * 4096 + k0;
            #pragma unroll
            for (int j = 0; j < 8; ++j) v[j] = p[j];
        } else if (n < 256) {
            int s = n - 128;
            #pragma unroll
            for (int j = 0; j < 8; ++j) {
                int k = k0 + j;
                v[j] = (k < 2048) ? Br[(size_t)k * 128 + s]
                                  : -Bi[(size_t)(k - 2048) * 128 + s];
            }
        } else {
            int s = n - 256;
            #pragma unroll
            for (int j = 0; j < 8; ++j) {
                int k = k0 + j;
                v[j] = (k < 2048) ? Bi[(size_t)k * 128 + s]
                                  : Br[(size_t)(k - 2048) * 128 + s];
            }
        }
        dsth = W1h + (size_t)id * 8; dstl = W1l + (size_t)id * 8;
    } else if (slot < W1_SLOTS + W2_SLOTS) {
        int s2 = slot - W1_SLOTS;
        int kt = s2 / 8, nf = s2 % 8;
        int s  = nf * 16 + (lane & 15);
        int k0 = kt * 32 + 8 * (lane >> 4);
        const float* p = pg_w + (size_t)s * 2048 + k0;
        #pragma unroll
        for (int j = 0; j < 8; ++j) v[j] = p[j];
        dsth = W2h + (size_t)(id - W1_SLOTS * 64) * 8;
        dstl = W2l + (size_t)(id - W1_SLOTS * 64) * 8;
    } else {
        int s3 = slot - W1_SLOTS - W2_SLOTS;
        int kt = s3 / 256, nf = s3 % 256;
        int n  = nf * 16 + (lane & 15);
        int d = n >> 1, comp = n & 1;
        int k0 = kt * 32 + 8 * (lane >> 4);
        #pragma unroll
        for (int j = 0; j < 8; ++j) {
            int k = k0 + j;
            int s = k & 127;
            float c;
            if (k < 128) c = comp ? Ci[(size_t)s * 2048 + d] : Cr[(size_t)s * 2048 + d];
            else         c = comp ? Cr[(size_t)s * 2048 + d] : -Ci[(size_t)s * 2048 + d];
            v[j] = c;
        }
        dsth = W3h + (size_t)(id - (W1_SLOTS + W2_SLOTS) * 64) * 8;
        dstl = W3l + (size_t)(id - (W1_SLOTS + W2_SLOTS) * 64) * 8;
    }
    bf16x8 hv, lv;
    #pragma unroll
    for (int j = 0; j < 8; ++j) {
        unsigned short h = bf16h(v[j]);
        hv[j] = (short)h;
        lv[j] = (short)bf16h(v[j] - bf2f(h));
    }
    *(bf16x8*)dsth = hv;
    *(bf16x8*)dstl = lv;
}

// ---------------------------------------------------------------------------
// Kernel 1: fused projections via split-bf16 MFMA (hh + hl + lh products).
// 256 blocks x 512 thr (8 waves). BM=64; waves N-split: wave w owns GEMM1
// cols [48w,48w+48) and GEMM2 col-frag w. Per 64-d block: stage xr/xi/|x|
// hi+lo fragment-linear into LDS (48 KB, union'd with 64 KB epilogue buf).
// ---------------------------------------------------------------------------
__global__ __launch_bounds__(512, 2) void phase1(
    const float* __restrict__ x,        // (M, DIM, 2)
    const short* __restrict__ W1h, const short* __restrict__ W1l,
    const short* __restrict__ W2h, const short* __restrict__ W2l,
    const float* __restrict__ log_A_real,
    const float* __restrict__ log_A_imag,
    const float* __restrict__ dt_b,
    const float* __restrict__ dt_bias,
    const float* __restrict__ pg_b,
    float* __restrict__ ABx)            // (M,S) float4 (Ar,Ai,Bxr,Bxi)
{
    const int tid  = threadIdx.x;
    const int lane = tid & 63;
    const int wv   = tid >> 6;
    const int m0   = blockIdx.x * 64;

    // streams: 0 xr_hi, 1 xr_lo, 2 xi_hi, 3 xi_lo, 4 cb_hi, 5 cb_lo
    __shared__ __align__(16) union SmemT {
        short comp[6][2][4][64][8];   // [stream][kf][mf][lane][j]  48 KB
        float ep[32][512];            // epilogue exchange           64 KB
    } smem;

    f32x4 c1[3][4];   // [nf_local][mf]
    f32x4 c2[4];      // [mf]
    #pragma unroll
    for (int n = 0; n < 3; ++n)
        #pragma unroll
        for (int m = 0; m < 4; ++m) c1[n][m] = (f32x4){0.f,0.f,0.f,0.f};
    #pragma unroll
    for (int m = 0; m < 4; ++m) c2[m] = (f32x4){0.f,0.f,0.f,0.f};

    const float2* x2 = (const float2*)x;
    // staging persona: row = tid>>3 (0..63), 8 consecutive d per thread
    const int srow = tid >> 3;
    const int sdg  = tid & 7;          // d_local = sdg*8 + j
    const int smf  = srow >> 4;
    const int skf  = sdg >> 2;         // = d_local>>5
    const int spl  = (srow & 15) + 16 * (sdg & 3);   // lane-slot = r15 + 16*lg

    float4 q[4];
    {
        const float4* xp = (const float4*)(x2 + (size_t)(m0 + srow) * DIMC + sdg * 8);
        #pragma unroll
        for (int i = 0; i < 4; ++i) q[i] = xp[i];
    }

    for (int db = 0; db < 32; ++db) {
        __syncthreads();   // prior compute done reading lds
        {
            bf16x8 vxh, vxl, vih, vil, vch, vcl;
            #pragma unroll
            for (int j = 0; j < 8; ++j) {
                int qi = j >> 1;
                float xr = (j & 1) ? q[qi].z : q[qi].x;
                float xi = (j & 1) ? q[qi].w : q[qi].y;
                unsigned short h1 = bf16h(xr);
                vxh[j] = (short)h1; vxl[j] = (short)bf16h(xr - bf2f(h1));
                unsigned short h2 = bf16h(xi);
                vih[j] = (short)h2; vil[j] = (short)bf16h(xi - bf2f(h2));
                float cb = sqrtf(fmaf(xr, xr, xi * xi));
                unsigned short h3 = bf16h(cb);
                vch[j] = (short)h3; vcl[j] = (short)bf16h(cb - bf2f(h3));
            }
            *(bf16x8*)&smem.comp[0][skf][smf][spl][0] = vxh;
            *(bf16x8*)&smem.comp[1][skf][smf][spl][0] = vxl;
            *(bf16x8*)&smem.comp[2][skf][smf][spl][0] = vih;
            *(bf16x8*)&smem.comp[3][skf][smf][spl][0] = vil;
            *(bf16x8*)&smem.comp[4][skf][smf][spl][0] = vch;
            *(bf16x8*)&smem.comp[5][skf][smf][spl][0] = vcl;
        }
        __syncthreads();
        if (db < 31) {   // prefetch next d-block during compute
            const float4* xp = (const float4*)(x2 + (size_t)(m0 + srow) * DIMC
                                               + (db + 1) * 64 + sdg * 8);
            #pragma unroll
            for (int i = 0; i < 4; ++i) q[i] = xp[i];
        }
        const int KTb = db * 2;
        #pragma unroll
        for (int kf = 0; kf < 2; ++kf) {
            bf16x8 ah[4], al[4];
            // ---- xr stream vs W1[ktile = KTb+kf] ----
            #pragma unroll
            for (int mf = 0; mf < 4; ++mf) {
                ah[mf] = *(const bf16x8*)&smem.comp[0][kf][mf][lane][0];
                al[mf] = *(const bf16x8*)&smem.comp[1][kf][mf][lane][0];
            }
            {
                size_t base = ((size_t)(KTb + kf) * 24 + wv * 3) * 64 + lane;
                const bf16x8* bh_p = (const bf16x8*)W1h + base;
                const bf16x8* bl_p = (const bf16x8*)W1l + base;
                #pragma unroll
                for (int nf = 0; nf < 3; ++nf) {
                    bf16x8 bh = bh_p[nf * 64], bl = bl_p[nf * 64];
                    #pragma unroll
                    for (int mf = 0; mf < 4; ++mf) {
                        f32x4 c = c1[nf][mf];
                        c = MFMA(ah[mf], bh, c);
                        c = MFMA(ah[mf], bl, c);
                        c = MFMA(al[mf], bh, c);
                        c1[nf][mf] = c;
                    }
                }
            }
            // ---- xi stream vs W1[ktile = 64 + KTb+kf] ----
            #pragma unroll
            for (int mf = 0; mf < 4; ++mf) {
                ah[mf] = *(const bf16x8*)&smem.comp[2][kf][mf][lane][0];
                al[mf] = *(const bf16x8*)&smem.comp[3][kf][mf][lane][0];
            }
            {
                size_t base = ((size_t)(64 + KTb + kf) * 24 + wv * 3) * 64 + lane;
                const bf16x8* bh_p = (const bf16x8*)W1h + base;
                const bf16x8* bl_p = (const bf16x8*)W1l + base;
                #pragma unroll
                for (int nf = 0; nf < 3; ++nf) {
                    bf16x8 bh = bh_p[nf * 64], bl = bl_p[nf * 64];
                    #pragma unroll
                    for (int mf = 0; mf < 4; ++mf) {
                        f32x4 c = c1[nf][mf];
                        c = MFMA(ah[mf], bh, c);
                        c = MFMA(ah[mf], bl, c);
                        c = MFMA(al[mf], bh, c);
                        c1[nf][mf] = c;
                    }
                }
            }
            // ---- cb stream vs W2 ----
            #pragma unroll
            for (int mf = 0; mf < 4; ++mf) {
                ah[mf] = *(const bf16x8*)&smem.comp[4][kf][mf][lane][0];
                al[mf] = *(const bf16x8*)&smem.comp[5][kf][mf][lane][0];
            }
            {
                size_t base = ((size_t)(KTb + kf) * 8 + wv) * 64 + lane;
                bf16x8 bh = ((const bf16x8*)W2h)[base];
                bf16x8 bl = ((const bf16x8*)W2l)[base];
                #pragma unroll
                for (int mf = 0; mf < 4; ++mf) {
                    f32x4 c = c2[mf];
                    c = MFMA(ah[mf], bh, c);
                    c = MFMA(ah[mf], bl, c);
                    c = MFMA(al[mf], bh, c);
                    c2[mf] = c;
                }
            }
        }
    }
    __syncthreads();

    // ---- fused epilogue via LDS exchange (32 rows x 512 cols f32) ----
    float* ep = &smem.ep[0][0];
    const int es = tid & 127;
    const int eq = tid >> 7;          // 0..3
    float eAr  = expf(log_A_real[es]);
    float egr  = cosf(log_A_imag[es]);
    float egi  = sinf(log_A_imag[es]);
    float bsum = dt_b[es] + dt_bias[es];
    float pgb  = pg_b[es];
    float4* AB4 = (float4*)ABx;

    #pragma unroll
    for (int half = 0; half < 2; ++half) {
        #pragma unroll
        for (int mfh = 0; mfh < 2; ++mfh) {
            int mf = half * 2 + mfh;
            int rl = mfh * 16 + (lane >> 4) * 4;
            #pragma unroll
            for (int nf = 0; nf < 3; ++nf) {
                f32x4 c = c1[nf][mf];
                int col = wv * 48 + nf * 16 + (lane & 15);
                #pragma unroll
                for (int r = 0; r < 4; ++r) ep[(rl + r) * 512 + col] = c[r];
            }
            {
                f32x4 c = c2[mf];
                int col = 384 + wv * 16 + (lane & 15);
                #pragma unroll
                for (int r = 0; r < 4; ++r) ep[(rl + r) * 512 + col] = c[r];
            }
        }
        __syncthreads();
        #pragma unroll
        for (int i = 0; i < 8; ++i) {
            int rl = eq + i * 4;
            float zd   = ep[rl * 512 + es]       + bsum;
            float abr  = ep[rl * 512 + 128 + es];
            float abi  = ep[rl * 512 + 256 + es];
            float zp   = ep[rl * 512 + 384 + es] + pgb;
            float dt   = fmaxf(zd, 0.f) + log1pf(expf(-fabsf(zd)));
            float amag = expf(-dt * eAr);
            float pr   = 1.f / (1.f + expf(-zp));
            float omp  = 1.f - pr;
            float Ar_  = fmaf(omp, amag * egr, pr);
            float Ai_  = omp * amag * egi;
            float sc   = omp * dt;
            AB4[(size_t)(m0 + half * 32 + rl) * SC + es] =
                make_float4(Ar_, Ai_, sc * abr, sc * abi);
        }
        __syncthreads();
    }
}

// ---------------------------------------------------------------------------
// Kernel 2a: per-chunk reduce. Grid = B*NC = 1024, block = 128.
// ---------------------------------------------------------------------------
__global__ void scan_reduce(const float* __restrict__ ABx,
                            float* __restrict__ aggAB) {
    int s = threadIdx.x;
    int c = blockIdx.x & (NC-1);
    int b = blockIdx.x >> 8;
    const float4* AB4 = (const float4*)ABx;
    size_t base = ((size_t)(b * LL + c * LCH) * SC + s);
    float4 v = AB4[base];
    float ar = v.x, ai = v.y, br = v.z, bi = v.w;
    #pragma unroll
    for (int t = 1; t < LCH; ++t) {
        float4 u = AB4[base + (size_t)t * SC];
        float nar = ar*u.x - ai*u.y;
        float nai = ar*u.y + ai*u.x;
        float nbr = br*u.x - bi*u.y + u.z;
        float nbi = br*u.y + bi*u.x + u.w;
        ar = nar; ai = nai; br = nbr; bi = nbi;
    }
    ((float4*)aggAB)[(size_t)blockIdx.x * SC + s] = make_float4(ar, ai, br, bi);
}

// ---------------------------------------------------------------------------
// Kernel 2b: exclusive scan of chunk aggregates (spine). 512 threads total.
// ---------------------------------------------------------------------------
__global__ void scan_spine(const float* __restrict__ aggAB,
                           float* __restrict__ preB) {
    int t = threadIdx.x + blockIdx.x * blockDim.x;   // 0..511
    int s = t & 127, b = t >> 7;
    const float4* A4 = (const float4*)aggAB;
    float2* P2 = (float2*)preB;
    float pa_r = 1.f, pa_i = 0.f, pb_r = 0.f, pb_i = 0.f;
    for (int c = 0; c < NC; ++c) {
        size_t idx = (size_t)(b * NC + c) * SC + s;
        P2[idx] = make_float2(pb_r, pb_i);
        float4 a = A4[idx];
        float nar = pa_r*a.x - pa_i*a.y;
        float nai = pa_r*a.y + pa_i*a.x;
        float nbr = pb_r*a.x - pb_i*a.y + a.z;
        float nbi = pb_r*a.y + pb_i*a.x + a.w;
        pa_r = nar; pa_i = nai; pb_r = nbr; pb_i = nbi;
    }
}

// ---------------------------------------------------------------------------
// Kernel 2c: apply prefixes; h written IN-PLACE into ABx .xy (same-thread
// read-then-write, no race; saves the 16 MB hbuf). Grid = B*NC = 1024.
// ---------------------------------------------------------------------------
__global__ void scan_apply(float* __restrict__ ABx,
                           const float* __restrict__ preB,
                           float* __restrict__ d_out) {
    int s = threadIdx.x;
    int c = blockIdx.x & (NC-1);
    int b = blockIdx.x >> 8;
    float4* AB4 = (float4*)ABx;
    float2 hp = ((const float2*)preB)[(size_t)blockIdx.x * SC + s];
    float hr = hp.x, hi = hp.y;
    size_t base = ((size_t)(b * LL + c * LCH) * SC + s);
    #pragma unroll
    for (int t = 0; t < LCH; ++t) {
        size_t idx = base + (size_t)t * SC;
        float4 u = AB4[idx];
        float nr = u.x*hr - u.y*hi + u.z;
        float ni = u.x*hi + u.y*hr + u.w;
        hr = nr; hi = ni;
        ((float2*)&AB4[idx])[0] = make_float2(hr, hi);
    }
    if (c == NC - 1) {
        float2* hl = (float2*)(d_out + (size_t)MM * DIMC * 2);
        hl[b * SC + s] = make_float2(hr, hi);
    }
}

// ---------------------------------------------------------------------------
// Kernel 3: y = h @ (Cr + i Ci) + D*x via split-bf16 MFMA.
// Grid = 2048 (bn = blk&7 XCD-pins the W3 slice; bm = blk>>3).
// 512 thr (8 waves N-split). BM=64, BN=512, K=256 staged once. LDS 64 KB.
// ---------------------------------------------------------------------------
__global__ __launch_bounds__(512, 2) void phase3(
    const float* __restrict__ ABx,     // .xy = (hr, hi) after scan_apply
    const short* __restrict__ W3h, const short* __restrict__ W3l,
    const float* __restrict__ x,
    const float* __restrict__ Dw,
    float* __restrict__ out)
{
    const int tid  = threadIdx.x;
    const int lane = tid & 63;
    const int wv   = tid >> 6;
    const int bn   = blockIdx.x & 7;
    const int bm   = blockIdx.x >> 3;
    const int m0   = bm * 64;

    __shared__ __align__(16) short ldsA[2][8][4][64][8];   // 64 KB

    // stage h: k = s for h_re (ktiles 0..3), 128+s for h_im (ktiles 4..7)
    {
        int row = tid >> 3, sg = tid & 7;
        int mf = row >> 4, r15 = row & 15;
        const float4* hp = (const float4*)ABx + (size_t)(m0 + row) * SC + sg * 16;
        #pragma unroll
        for (int e8 = 0; e8 < 2; ++e8) {
            int t2 = sg * 2 + e8;          // s-run = t2*8 .. t2*8+7
            int kfr = t2 >> 2, lg = t2 & 3;
            int pl = r15 + 16 * lg;
            bf16x8 rh, rl, ih, il;
            #pragma unroll
            for (int j = 0; j < 8; ++j) {
                float4 u = hp[e8 * 8 + j];
                unsigned short h1 = bf16h(u.x);
                rh[j] = (short)h1; rl[j] = (short)bf16h(u.x - bf2f(h1));
                unsigned short h2 = bf16h(u.y);
                ih[j] = (short)h2; il[j] = (short)bf16h(u.y - bf2f(h2));
            }
            *(bf16x8*)&ldsA[0][kfr][mf][pl][0]     = rh;
            *(bf16x8*)&ldsA[1][kfr][mf][pl][0]     = rl;
            *(bf16x8*)&ldsA[0][kfr + 4][mf][pl][0] = ih;
            *(bf16x8*)&ldsA[1][kfr + 4][mf][pl][0] = il;
        }
    }
    __syncthreads();

    f32x4 c[4][4];   // [nf_local][mf]
    #pragma unroll
    for (int n = 0; n < 4; ++n)
        #pragma unroll
        for (int m = 0; m < 4; ++m) c[n][m] = (f32x4){0.f,0.f,0.f,0.f};

    #pragma unroll
    for (int kf = 0; kf < 8; ++kf) {
        bf16x8 ah[4], al[4];
        #pragma unroll
        for (int mf = 0; mf < 4; ++mf) {
            ah[mf] = *(const bf16x8*)&ldsA[0][kf][mf][lane][0];
            al[mf] = *(const bf16x8*)&ldsA[1][kf][mf][lane][0];
        }
        size_t base = ((size_t)kf * 256 + bn * 32 + wv * 4) * 64 + lane;
        const bf16x8* bh_p = (const bf16x8*)W3h + base;
        const bf16x8* bl_p = (const bf16x8*)W3l + base;
        #pragma unroll
        for (int nf = 0; nf < 4; ++nf) {
            bf16x8 bh = bh_p[nf * 64], bl = bl_p[nf * 64];
            #pragma unroll
            for (int mf = 0; mf < 4; ++mf) {
                f32x4 cc = c[nf][mf];
                cc = MFMA(ah[mf], bh, cc);
                cc = MFMA(ah[mf], bl, cc);
                cc = MFMA(al[mf], bh, cc);
                c[nf][mf] = cc;
            }
        }
    }

    // epilogue: + D*x, coalesced stores (n = d*2+comp is the flat out index)
    const float2* x2  = (const float2*)x;
    const float2* Dw2 = (const float2*)Dw;
    #pragma unroll
    for (int nf = 0; nf < 4; ++nf) {
        int n = bn * 512 + wv * 64 + nf * 16 + (lane & 15);
        int d = n >> 1, comp = n & 1;
        float2 dw = Dw2[d];
        #pragma unroll
        for (int mf = 0; mf < 4; ++mf) {
            f32x4 cc = c[nf][mf];
            int mbase = m0 + mf * 16 + (lane >> 4) * 4;
            #pragma unroll
            for (int r = 0; r < 4; ++r) {
                int m = mbase + r;
                float2 xv = x2[(size_t)m * DIMC + d];
                float val = cc[r] + (comp ? fmaf(dw.x, xv.y,  dw.y * xv.x)
                                          : fmaf(dw.x, xv.x, -dw.y * xv.y));
                out[(size_t)m * 4096 + n] = val;
            }
        }
    }
}

// ---------------------------------------------------------------------------
extern "C" void kernel_launch(void* const* d_in, const int* in_sizes, int n_in,
                              void* d_out, int out_size, void* d_ws, size_t ws_size,
                              hipStream_t stream) {
    const float* x          = (const float*)d_in[0];
    const float* log_A_real = (const float*)d_in[1];
    const float* log_A_imag = (const float*)d_in[2];
    const float* Dw         = (const float*)d_in[3];
    const float* dt_w       = (const float*)d_in[4];
    const float* dt_b       = (const float*)d_in[5];
    const float* dt_bias    = (const float*)d_in[6];
    const float* Br         = (const float*)d_in[7];
    const float* Bi         = (const float*)d_in[8];
    const float* Cr         = (const float*)d_in[9];
    const float* Ci         = (const float*)d_in[10];
    const float* pg_w       = (const float*)d_in[11];
    const float* pg_b       = (const float*)d_in[12];

    float* out = (float*)d_out;
    float* ws  = (float*)d_ws;

    // Workspace (floats): total 12,058,624 = 48.2 MB (< 53.5 MB proven safe)
    short* W1h = (short*)ws;                          // 1,572,864 shorts
    short* W1l = W1h + (size_t)W1_SLOTS * 64 * 8;     // 1,572,864
    short* W2h = W1l + (size_t)W1_SLOTS * 64 * 8;     //   262,144
    short* W2l = W2h + (size_t)W2_SLOTS * 64 * 8;     //   262,144
    float* aggAB = ws + 1835008;                      //   524,288 floats
    float* preB  = aggAB + (size_t)BB * NC * SC * 4;  //   262,144
    float* ABx   = ws + 2621440;                      // 8,388,608
    short* W3h   = (short*)(ws + 2621440 + 8388608);  // 1,048,576 shorts
    short* W3l   = W3h + (size_t)W3_SLOTS * 64 * 8;   // 1,048,576

    hipLaunchKernelGGL(prep_w, dim3((W1_SLOTS+W2_SLOTS+W3_SLOTS)*64/256), dim3(256), 0, stream,
                       dt_w, Br, Bi, pg_w, Cr, Ci, W1h, W1l, W2h, W2l, W3h, W3l);
    hipLaunchKernelGGL(phase1, dim3(MM/64), dim3(512), 0, stream,
                       x, W1h, W1l, W2h, W2l, log_A_real, log_A_imag,
                       dt_b, dt_bias, pg_b, ABx);
    hipLaunchKernelGGL(scan_reduce, dim3(BB*NC), dim3(128), 0, stream,
                       ABx, aggAB);
    hipLaunchKernelGGL(scan_spine, dim3(2), dim3(256), 0, stream,
                       aggAB, preB);
    hipLaunchKernelGGL(scan_apply, dim3(BB*NC), dim3(128), 0, stream,
                       ABx, preB, out);
    hipLaunchKernelGGL(phase3, dim3(2048), dim3(512), 0, stream,
                       ABx, W3h, W3l, x, Dw, out);
}

// Round 5
// 945.018 us; speedup vs baseline: 2.6547x; 1.1242x over previous
//
#include <hip/hip_runtime.h>
#include <math.h>

// Problem constants
#define BB   4
#define LL   4096
#define DIMC 2048
#define SC   128
#define MM   (BB*LL)        // 16384 rows
#define NC   256            // scan chunks per sequence
#define LCH  (LL/NC)        // 16 = chunk length

typedef __attribute__((ext_vector_type(8))) short bf16x8;
typedef __attribute__((ext_vector_type(4))) float f32x4;

#define MFMA(a,b,c) __builtin_amdgcn_mfma_f32_16x16x32_bf16(a,b,c,0,0,0)

// RNE float -> bf16 bits
__device__ inline unsigned short bf16h(float v) {
    unsigned u = __float_as_uint(v);
    return (unsigned short)((u + 0x7FFFu + ((u >> 16) & 1u)) >> 16);
}
__device__ inline float bf2f(unsigned short h) {
    return __uint_as_float(((unsigned)h) << 16);
}

// ---------------------------------------------------------------------------
// Kernel 0: build fragment-linear bf16 hi/lo weights.
// MFMA 16x16x32 fragment: slot = (ktile*NF + nfrag)*64 + lane, 8 bf16/slot:
// element j = W[k = ktile*32 + 8*(lane>>4) + j][n = nfrag*16 + (lane&15)].
// W1 (K=4096, N=384): n 0..127 dt ([xr;xi] @ dt_w rows), 128..255 Bx_re
// ([Br;-Bi]), 256..383 Bx_im ([Bi;Br]).  W2 (K=2048, N=128): pg_w^T.
// W3 (K=256, N=4096): n = d*2+comp; comp0 (yr): [Cr;-Ci], comp1 (yi): [Ci;Cr].
// ---------------------------------------------------------------------------
#define W1_SLOTS (128*24)
#define W2_SLOTS (64*8)
#define W3_SLOTS (8*256)
__global__ void prep_w(const float* __restrict__ dt_w,
                       const float* __restrict__ Br,
                       const float* __restrict__ Bi,
                       const float* __restrict__ pg_w,
                       const float* __restrict__ Cr,
                       const float* __restrict__ Ci,
                       short* __restrict__ W1h, short* __restrict__ W1l,
                       short* __restrict__ W2h, short* __restrict__ W2l,
                       short* __restrict__ W3h, short* __restrict__ W3l) {
    int id = threadIdx.x + blockIdx.x * 256;
    int lane = id & 63;
    int slot = id >> 6;
    float v[8];
    short* dsth; short* dstl;
    if (slot < W1_SLOTS) {
        int kt = slot / 24, nf = slot % 24;
        int n  = nf * 16 + (lane & 15);
        int k0 = kt * 32 + 8 * (lane >> 4);
        if (n < 128) {
            const float* p = dt_w + (size_t)n * 4096 + k0;
            #pragma unroll
            for (int j = 0; j < 8; ++j) v[j] = p[j];
        } else if (n < 256) {
            int s = n - 128;
            #pragma unroll
            for (int j = 0; j < 8; ++j) {
                int k = k0 + j;
                v[j] = (k < 2048) ? Br[(size_t)k * 128 + s]
                                  : -Bi[(size_t)(k - 2048) * 128 + s];
            }
        } else {
            int s = n - 256;
            #pragma unroll
            for (int j = 0; j < 8; ++j) {
                int k = k0 + j;
                v[j] = (k < 2048) ? Bi[(size_t)k * 128 + s]
                                  : Br[(size_t)(k - 2048) * 128 + s];
            }
        }
        dsth = W1h + (size_t)id * 8; dstl = W1l + (size_t)id * 8;
    } else if (slot < W1_SLOTS + W2_SLOTS) {
        int s2 = slot - W1_SLOTS;
        int kt = s2 / 8, nf = s2 % 8;
        int s  = nf * 16 + (lane & 15);
        int k0 = kt * 32 + 8 * (lane >> 4);
        const float* p = pg_w + (size_t)s * 2048 + k0;
        #pragma unroll
        for (int j = 0; j < 8; ++j) v[j] = p[j];
        dsth = W2h + (size_t)(id - W1_SLOTS * 64) * 8;
        dstl = W2l + (size_t)(id - W1_SLOTS * 64) * 8;
    } else {
        int s3 = slot - W1_SLOTS - W2_SLOTS;
        int kt = s3 / 256, nf = s3 % 256;
        int n  = nf * 16 + (lane & 15);
        int d = n >> 1, comp = n & 1;
        int k0 = kt * 32 + 8 * (lane >> 4);
        #pragma unroll
        for (int j = 0; j < 8; ++j) {
            int k = k0 + j;
            int s = k & 127;
            float c;
            if (k < 128) c = comp ? Ci[(size_t)s * 2048 + d] : Cr[(size_t)s * 2048 + d];
            else         c = comp ? Cr[(size_t)s * 2048 + d] : -Ci[(size_t)s * 2048 + d];
            v[j] = c;
        }
        dsth = W3h + (size_t)(id - (W1_SLOTS + W2_SLOTS) * 64) * 8;
        dstl = W3l + (size_t)(id - (W1_SLOTS + W2_SLOTS) * 64) * 8;
    }
    bf16x8 hv, lv;
    #pragma unroll
    for (int j = 0; j < 8; ++j) {
        unsigned short h = bf16h(v[j]);
        hv[j] = (short)h;
        lv[j] = (short)bf16h(v[j] - bf2f(h));
    }
    *(bf16x8*)dsth = hv;
    *(bf16x8*)dstl = lv;
}

// ---------------------------------------------------------------------------
// Kernel 1: fused projections via split-bf16 MFMA (hh + hl + lh products).
// 256 blocks x 512 thr (8 waves). BM=64; waves N-split: wave w owns GEMM1
// cols [48w,48w+48) and GEMM2 col-frag w. Per 64-d block: stage xr/xi/|x|
// hi+lo fragment-linear into LDS (48 KB, union'd with 64 KB epilogue buf).
// ---------------------------------------------------------------------------
__global__ __launch_bounds__(512, 2) void phase1(
    const float* __restrict__ x,        // (M, DIM, 2)
    const short* __restrict__ W1h, const short* __restrict__ W1l,
    const short* __restrict__ W2h, const short* __restrict__ W2l,
    const float* __restrict__ log_A_real,
    const float* __restrict__ log_A_imag,
    const float* __restrict__ dt_b,
    const float* __restrict__ dt_bias,
    const float* __restrict__ pg_b,
    float* __restrict__ ABx)            // (M,S) float4 (Ar,Ai,Bxr,Bxi)
{
    const int tid  = threadIdx.x;
    const int lane = tid & 63;
    const int wv   = tid >> 6;
    const int m0   = blockIdx.x * 64;

    // streams: 0 xr_hi, 1 xr_lo, 2 xi_hi, 3 xi_lo, 4 cb_hi, 5 cb_lo
    __shared__ __align__(16) union SmemT {
        short comp[6][2][4][64][8];   // [stream][kf][mf][lane][j]  48 KB
        float ep[32][512];            // epilogue exchange           64 KB
    } smem;

    f32x4 c1[3][4];   // [nf_local][mf]
    f32x4 c2[4];      // [mf]
    #pragma unroll
    for (int n = 0; n < 3; ++n)
        #pragma unroll
        for (int m = 0; m < 4; ++m) c1[n][m] = (f32x4){0.f,0.f,0.f,0.f};
    #pragma unroll
    for (int m = 0; m < 4; ++m) c2[m] = (f32x4){0.f,0.f,0.f,0.f};

    const float2* x2 = (const float2*)x;
    // staging persona: row = tid>>3 (0..63), 8 consecutive d per thread
    const int srow = tid >> 3;
    const int sdg  = tid & 7;          // d_local = sdg*8 + j
    const int smf  = srow >> 4;
    const int skf  = sdg >> 2;         // = d_local>>5
    const int spl  = (srow & 15) + 16 * (sdg & 3);   // lane-slot = r15 + 16*lg

    float4 q[4];
    {
        const float4* xp = (const float4*)(x2 + (size_t)(m0 + srow) * DIMC + sdg * 8);
        #pragma unroll
        for (int i = 0; i < 4; ++i) q[i] = xp[i];
    }

    for (int db = 0; db < 32; ++db) {
        __syncthreads();   // prior compute done reading lds
        {
            bf16x8 vxh, vxl, vih, vil, vch, vcl;
            #pragma unroll
            for (int j = 0; j < 8; ++j) {
                int qi = j >> 1;
                float xr = (j & 1) ? q[qi].z : q[qi].x;
                float xi = (j & 1) ? q[qi].w : q[qi].y;
                unsigned short h1 = bf16h(xr);
                vxh[j] = (short)h1; vxl[j] = (short)bf16h(xr - bf2f(h1));
                unsigned short h2 = bf16h(xi);
                vih[j] = (short)h2; vil[j] = (short)bf16h(xi - bf2f(h2));
                float cb = sqrtf(fmaf(xr, xr, xi * xi));
                unsigned short h3 = bf16h(cb);
                vch[j] = (short)h3; vcl[j] = (short)bf16h(cb - bf2f(h3));
            }
            *(bf16x8*)&smem.comp[0][skf][smf][spl][0] = vxh;
            *(bf16x8*)&smem.comp[1][skf][smf][spl][0] = vxl;
            *(bf16x8*)&smem.comp[2][skf][smf][spl][0] = vih;
            *(bf16x8*)&smem.comp[3][skf][smf][spl][0] = vil;
            *(bf16x8*)&smem.comp[4][skf][smf][spl][0] = vch;
            *(bf16x8*)&smem.comp[5][skf][smf][spl][0] = vcl;
        }
        __syncthreads();
        if (db < 31) {   // prefetch next d-block during compute
            const float4* xp = (const float4*)(x2 + (size_t)(m0 + srow) * DIMC
                                               + (db + 1) * 64 + sdg * 8);
            #pragma unroll
            for (int i = 0; i < 4; ++i) q[i] = xp[i];
        }
        const int KTb = db * 2;
        #pragma unroll
        for (int kf = 0; kf < 2; ++kf) {
            bf16x8 ah[4], al[4];
            // ---- xr stream vs W1[ktile = KTb+kf] ----
            #pragma unroll
            for (int mf = 0; mf < 4; ++mf) {
                ah[mf] = *(const bf16x8*)&smem.comp[0][kf][mf][lane][0];
                al[mf] = *(const bf16x8*)&smem.comp[1][kf][mf][lane][0];
            }
            {
                size_t base = ((size_t)(KTb + kf) * 24 + wv * 3) * 64 + lane;
                const bf16x8* bh_p = (const bf16x8*)W1h + base;
                const bf16x8* bl_p = (const bf16x8*)W1l + base;
                #pragma unroll
                for (int nf = 0; nf < 3; ++nf) {
                    bf16x8 bh = bh_p[nf * 64], bl = bl_p[nf * 64];
                    #pragma unroll
                    for (int mf = 0; mf < 4; ++mf) {
                        f32x4 c = c1[nf][mf];
                        c = MFMA(ah[mf], bh, c);
                        c = MFMA(ah[mf], bl, c);
                        c = MFMA(al[mf], bh, c);
                        c1[nf][mf] = c;
                    }
                }
            }
            // ---- xi stream vs W1[ktile = 64 + KTb+kf] ----
            #pragma unroll
            for (int mf = 0; mf < 4; ++mf) {
                ah[mf] = *(const bf16x8*)&smem.comp[2][kf][mf][lane][0];
                al[mf] = *(const bf16x8*)&smem.comp[3][kf][mf][lane][0];
            }
            {
                size_t base = ((size_t)(64 + KTb + kf) * 24 + wv * 3) * 64 + lane;
                const bf16x8* bh_p = (const bf16x8*)W1h + base;
                const bf16x8* bl_p = (const bf16x8*)W1l + base;
                #pragma unroll
                for (int nf = 0; nf < 3; ++nf) {
                    bf16x8 bh = bh_p[nf * 64], bl = bl_p[nf * 64];
                    #pragma unroll
                    for (int mf = 0; mf < 4; ++mf) {
                        f32x4 c = c1[nf][mf];
                        c = MFMA(ah[mf], bh, c);
                        c = MFMA(ah[mf], bl, c);
                        c = MFMA(al[mf], bh, c);
                        c1[nf][mf] = c;
                    }
                }
            }
            // ---- cb stream vs W2 ----
            #pragma unroll
            for (int mf = 0; mf < 4; ++mf) {
                ah[mf] = *(const bf16x8*)&smem.comp[4][kf][mf][lane][0];
                al[mf] = *(const bf16x8*)&smem.comp[5][kf][mf][lane][0];
            }
            {
                size_t base = ((size_t)(KTb + kf) * 8 + wv) * 64 + lane;
                bf16x8 bh = ((const bf16x8*)W2h)[base];
                bf16x8 bl = ((const bf16x8*)W2l)[base];
                #pragma unroll
                for (int mf = 0; mf < 4; ++mf) {
                    f32x4 c = c2[mf];
                    c = MFMA(ah[mf], bh, c);
                    c = MFMA(ah[mf], bl, c);
                    c = MFMA(al[mf], bh, c);
                    c2[mf] = c;
                }
            }
        }
    }
    __syncthreads();

    // ---- fused epilogue via LDS exchange (32 rows x 512 cols f32) ----
    float* ep = &smem.ep[0][0];
    const int es = tid & 127;
    const int eq = tid >> 7;          // 0..3
    float eAr  = expf(log_A_real[es]);
    float egr  = cosf(log_A_imag[es]);
    float egi  = sinf(log_A_imag[es]);
    float bsum = dt_b[es] + dt_bias[es];
    float pgb  = pg_b[es];
    float4* AB4 = (float4*)ABx;

    #pragma unroll
    for (int half = 0; half < 2; ++half) {
        #pragma unroll
        for (int mfh = 0; mfh < 2; ++mfh) {
            int mf = half * 2 + mfh;
            int rl = mfh * 16 + (lane >> 4) * 4;
            #pragma unroll
            for (int nf = 0; nf < 3; ++nf) {
                f32x4 c = c1[nf][mf];
                int col = wv * 48 + nf * 16 + (lane & 15);
                #pragma unroll
                for (int r = 0; r < 4; ++r) ep[(rl + r) * 512 + col] = c[r];
            }
            {
                f32x4 c = c2[mf];
                int col = 384 + wv * 16 + (lane & 15);
                #pragma unroll
                for (int r = 0; r < 4; ++r) ep[(rl + r) * 512 + col] = c[r];
            }
        }
        __syncthreads();
        #pragma unroll
        for (int i = 0; i < 8; ++i) {
            int rl = eq + i * 4;
            float zd   = ep[rl * 512 + es]       + bsum;
            float abr  = ep[rl * 512 + 128 + es];
            float abi  = ep[rl * 512 + 256 + es];
            float zp   = ep[rl * 512 + 384 + es] + pgb;
            float dt   = fmaxf(zd, 0.f) + log1pf(expf(-fabsf(zd)));
            float amag = expf(-dt * eAr);
            float pr   = 1.f / (1.f + expf(-zp));
            float omp  = 1.f - pr;
            float Ar_  = fmaf(omp, amag * egr, pr);
            float Ai_  = omp * amag * egi;
            float sc   = omp * dt;
            AB4[(size_t)(m0 + half * 32 + rl) * SC + es] =
                make_float4(Ar_, Ai_, sc * abr, sc * abi);
        }
        __syncthreads();
    }
}

// ---------------------------------------------------------------------------
// Kernel 2a: per-chunk reduce. Grid = B*NC = 1024, block = 128.
// ---------------------------------------------------------------------------
__global__ void scan_reduce(const float* __restrict__ ABx,
                            float* __restrict__ aggAB) {
    int s = threadIdx.x;
    int c = blockIdx.x & (NC-1);
    int b = blockIdx.x >> 8;
    const float4* AB4 = (const float4*)ABx;
    size_t base = ((size_t)(b * LL + c * LCH) * SC + s);
    float4 v = AB4[base];
    float ar = v.x, ai = v.y, br = v.z, bi = v.w;
    #pragma unroll
    for (int t = 1; t < LCH; ++t) {
        float4 u = AB4[base + (size_t)t * SC];
        float nar = ar*u.x - ai*u.y;
        float nai = ar*u.y + ai*u.x;
        float nbr = br*u.x - bi*u.y + u.z;
        float nbi = br*u.y + bi*u.x + u.w;
        ar = nar; ai = nai; br = nbr; bi = nbi;
    }
    ((float4*)aggAB)[(size_t)blockIdx.x * SC + s] = make_float4(ar, ai, br, bi);
}

// ---------------------------------------------------------------------------
// Kernel 2b: exclusive scan of chunk aggregates (spine). 512 threads total.
// ---------------------------------------------------------------------------
__global__ void scan_spine(const float* __restrict__ aggAB,
                           float* __restrict__ preB) {
    int t = threadIdx.x + blockIdx.x * blockDim.x;   // 0..511
    int s = t & 127, b = t >> 7;
    const float4* A4 = (const float4*)aggAB;
    float2* P2 = (float2*)preB;
    float pa_r = 1.f, pa_i = 0.f, pb_r = 0.f, pb_i = 0.f;
    for (int c = 0; c < NC; ++c) {
        size_t idx = (size_t)(b * NC + c) * SC + s;
        P2[idx] = make_float2(pb_r, pb_i);
        float4 a = A4[idx];
        float nar = pa_r*a.x - pa_i*a.y;
        float nai = pa_r*a.y + pa_i*a.x;
        float nbr = pb_r*a.x - pb_i*a.y + a.z;
        float nbi = pb_r*a.y + pb_i*a.x + a.w;
        pa_r = nar; pa_i = nai; pb_r = nbr; pb_i = nbi;
    }
}

// ---------------------------------------------------------------------------
// Kernel 2c: apply prefixes; h written IN-PLACE into ABx .xy (same-thread
// read-then-write, no race; saves the 16 MB hbuf). Grid = B*NC = 1024.
// ---------------------------------------------------------------------------
__global__ void scan_apply(float* __restrict__ ABx,
                           const float* __restrict__ preB,
                           float* __restrict__ d_out) {
    int s = threadIdx.x;
    int c = blockIdx.x & (NC-1);
    int b = blockIdx.x >> 8;
    float4* AB4 = (float4*)ABx;
    float2 hp = ((const float2*)preB)[(size_t)blockIdx.x * SC + s];
    float hr = hp.x, hi = hp.y;
    size_t base = ((size_t)(b * LL + c * LCH) * SC + s);
    #pragma unroll
    for (int t = 0; t < LCH; ++t) {
        size_t idx = base + (size_t)t * SC;
        float4 u = AB4[idx];
        float nr = u.x*hr - u.y*hi + u.z;
        float ni = u.x*hi + u.y*hr + u.w;
        hr = nr; hi = ni;
        ((float2*)&AB4[idx])[0] = make_float2(hr, hi);
    }
    if (c == NC - 1) {
        float2* hl = (float2*)(d_out + (size_t)MM * DIMC * 2);
        hl[b * SC + s] = make_float2(hr, hi);
    }
}

// ---------------------------------------------------------------------------
// Kernel 3: y = h @ (Cr + i Ci) + D*x via split-bf16 MFMA.
// v2: BM=32, LDS 32 KB, launch_bounds(512,6) -> 3 blocks/CU, 24 waves/CU
// (was 64KB/2 blocks/16 waves: latency-bound, all pipes <21%).
// Grid = 4096 (bn = blk&7 XCD-pins the W3 slice; bm = blk>>3).
// 512 thr (8 waves N-split). BM=32, BN=512, K=256 staged once.
// ---------------------------------------------------------------------------
__global__ __launch_bounds__(512, 6) void phase3(
    const float* __restrict__ ABx,     // .xy = (hr, hi) after scan_apply
    const short* __restrict__ W3h, const short* __restrict__ W3l,
    const float* __restrict__ x,
    const float* __restrict__ Dw,
    float* __restrict__ out)
{
    const int tid  = threadIdx.x;
    const int lane = tid & 63;
    const int wv   = tid >> 6;
    const int bn   = blockIdx.x & 7;
    const int bm   = blockIdx.x >> 3;
    const int m0   = bm * 32;

    __shared__ __align__(16) short ldsA[2][8][2][64][8];   // 32 KB

    // stage h: 32 rows x 128 s; thread = (row = tid>>4, sg = tid&15),
    // s-run = sg*8..sg*8+7 -> ktile kfr = sg>>2 (re), kfr+4 (im);
    // lane-slot = (row&15) + 16*(sg&3); mf = row>>4.
    {
        int row = tid >> 4, sg = tid & 15;
        int mf = row >> 4, r15 = row & 15;
        int kfr = sg >> 2, lg = sg & 3;
        int pl = r15 + 16 * lg;
        const float4* hp = (const float4*)ABx + (size_t)(m0 + row) * SC + sg * 8;
        bf16x8 rh, rl, ih, il;
        #pragma unroll
        for (int j = 0; j < 8; ++j) {
            float4 u = hp[j];
            unsigned short h1 = bf16h(u.x);
            rh[j] = (short)h1; rl[j] = (short)bf16h(u.x - bf2f(h1));
            unsigned short h2 = bf16h(u.y);
            ih[j] = (short)h2; il[j] = (short)bf16h(u.y - bf2f(h2));
        }
        *(bf16x8*)&ldsA[0][kfr][mf][pl][0]     = rh;
        *(bf16x8*)&ldsA[1][kfr][mf][pl][0]     = rl;
        *(bf16x8*)&ldsA[0][kfr + 4][mf][pl][0] = ih;
        *(bf16x8*)&ldsA[1][kfr + 4][mf][pl][0] = il;
    }
    __syncthreads();

    f32x4 c[4][2];   // [nf_local][mf]
    #pragma unroll
    for (int n = 0; n < 4; ++n)
        #pragma unroll
        for (int m = 0; m < 2; ++m) c[n][m] = (f32x4){0.f,0.f,0.f,0.f};

    #pragma unroll
    for (int kf = 0; kf < 8; ++kf) {
        bf16x8 ah[2], al[2];
        #pragma unroll
        for (int mf = 0; mf < 2; ++mf) {
            ah[mf] = *(const bf16x8*)&ldsA[0][kf][mf][lane][0];
            al[mf] = *(const bf16x8*)&ldsA[1][kf][mf][lane][0];
        }
        size_t base = ((size_t)kf * 256 + bn * 32 + wv * 4) * 64 + lane;
        const bf16x8* bh_p = (const bf16x8*)W3h + base;
        const bf16x8* bl_p = (const bf16x8*)W3l + base;
        #pragma unroll
        for (int nf = 0; nf < 4; ++nf) {
            bf16x8 bh = bh_p[nf * 64], bl = bl_p[nf * 64];
            #pragma unroll
            for (int mf = 0; mf < 2; ++mf) {
                f32x4 cc = c[nf][mf];
                cc = MFMA(ah[mf], bh, cc);
                cc = MFMA(ah[mf], bl, cc);
                cc = MFMA(al[mf], bh, cc);
                c[nf][mf] = cc;
            }
        }
    }

    // epilogue: + D*x, coalesced stores (n = d*2+comp is the flat out index)
    const float2* x2  = (const float2*)x;
    const float2* Dw2 = (const float2*)Dw;
    #pragma unroll
    for (int nf = 0; nf < 4; ++nf) {
        int n = bn * 512 + wv * 64 + nf * 16 + (lane & 15);
        int d = n >> 1, comp = n & 1;
        float2 dw = Dw2[d];
        #pragma unroll
        for (int mf = 0; mf < 2; ++mf) {
            f32x4 cc = c[nf][mf];
            int mbase = m0 + mf * 16 + (lane >> 4) * 4;
            #pragma unroll
            for (int r = 0; r < 4; ++r) {
                int m = mbase + r;
                float2 xv = x2[(size_t)m * DIMC + d];
                float val = cc[r] + (comp ? fmaf(dw.x, xv.y,  dw.y * xv.x)
                                          : fmaf(dw.x, xv.x, -dw.y * xv.y));
                out[(size_t)m * 4096 + n] = val;
            }
        }
    }
}

// ---------------------------------------------------------------------------
extern "C" void kernel_launch(void* const* d_in, const int* in_sizes, int n_in,
                              void* d_out, int out_size, void* d_ws, size_t ws_size,
                              hipStream_t stream) {
    const float* x          = (const float*)d_in[0];
    const float* log_A_real = (const float*)d_in[1];
    const float* log_A_imag = (const float*)d_in[2];
    const float* Dw         = (const float*)d_in[3];
    const float* dt_w       = (const float*)d_in[4];
    const float* dt_b       = (const float*)d_in[5];
    const float* dt_bias    = (const float*)d_in[6];
    const float* Br         = (const float*)d_in[7];
    const float* Bi         = (const float*)d_in[8];
    const float* Cr         = (const float*)d_in[9];
    const float* Ci         = (const float*)d_in[10];
    const float* pg_w       = (const float*)d_in[11];
    const float* pg_b       = (const float*)d_in[12];

    float* out = (float*)d_out;
    float* ws  = (float*)d_ws;

    // Workspace (floats): total 12,058,624 = 48.2 MB
    short* W1h = (short*)ws;                          // 1,572,864 shorts
    short* W1l = W1h + (size_t)W1_SLOTS * 64 * 8;     // 1,572,864
    short* W2h = W1l + (size_t)W1_SLOTS * 64 * 8;     //   262,144
    short* W2l = W2h + (size_t)W2_SLOTS * 64 * 8;     //   262,144
    float* aggAB = ws + 1835008;                      //   524,288 floats
    float* preB  = aggAB + (size_t)BB * NC * SC * 4;  //   262,144
    float* ABx   = ws + 2621440;                      // 8,388,608
    short* W3h   = (short*)(ws + 2621440 + 8388608);  // 1,048,576 shorts
    short* W3l   = W3h + (size_t)W3_SLOTS * 64 * 8;   // 1,048,576

    hipLaunchKernelGGL(prep_w, dim3((W1_SLOTS+W2_SLOTS+W3_SLOTS)*64/256), dim3(256), 0, stream,
                       dt_w, Br, Bi, pg_w, Cr, Ci, W1h, W1l, W2h, W2l, W3h, W3l);
    hipLaunchKernelGGL(phase1, dim3(MM/64), dim3(512), 0, stream,
                       x, W1h, W1l, W2h, W2l, log_A_real, log_A_imag,
                       dt_b, dt_bias, pg_b, ABx);
    hipLaunchKernelGGL(scan_reduce, dim3(BB*NC), dim3(128), 0, stream,
                       ABx, aggAB);
    hipLaunchKernelGGL(scan_spine, dim3(2), dim3(256), 0, stream,
                       aggAB, preB);
    hipLaunchKernelGGL(scan_apply, dim3(BB*NC), dim3(128), 0, stream,
                       ABx, preB, out);
    hipLaunchKernelGGL(phase3, dim3(4096), dim3(512), 0, stream,
                       ABx, W3h, W3l, x, Dw, out);
}